// Round 12
// baseline (1756.794 us; speedup 1.0000x reference)
//
#include <hip/hip_runtime.h>
#include <hip/hip_bf16.h>

#define T_STEPS 128
#define B_SZ    1024
#define IN_SZ   47
#define H_SZ    646
#define OUT_SZ  5

#define XK    96      // xs padded row stride (47 -> 96)
#define K0    768     // layer0 K = 96 + 672
#define K1    1344    // layer1 K = 672 + 672 (also the state-slab row stride)
#define N0PAD 704     // L0 packed-W cols (11 * 64, zero-padded)
#define N1PAD 672     // L1 packed-W cols
#define RING  17      // state ring slots per row-group (fresh-address coherence)
#define SLAB  172032  // 128 rows * 1344 cols, elements per rg slab
#define FSTR  160     // flag array stride (ints), 640 B -> no cross-line sharing

// tiles (r11-proven): L0 96-col x7 blocks, L1 48-col x14 blocks
#define NL0B  7
#define NL1B  14
#define NBLK  (8 * (NL0B + NL1B))   // 168

typedef __hip_bfloat16 bf16;
typedef unsigned short ush;
using frag8 = __attribute__((ext_vector_type(8))) short;  // 8 bf16
using f32x4 = __attribute__((ext_vector_type(4))) float;

// ---------------------------------------------------------------- prep kernels

__global__ void prep_xs(const float* __restrict__ xs, bf16* __restrict__ xs_pad) {
    int idx = blockIdx.x * blockDim.x + threadIdx.x;
    if (idx >= T_STEPS * B_SZ * XK) return;
    int k = idx % XK;
    int rb = idx / XK;
    float v = (k < IN_SZ) ? xs[(size_t)rb * IN_SZ + k] : 0.f;
    xs_pad[idx] = __float2bfloat16(v);
}

__global__ void pack_w0(const float* __restrict__ Wih, const float* __restrict__ Whh,
                        bf16* __restrict__ Wc) {
    int idx = blockIdx.x * blockDim.x + threadIdx.x;
    if (idx >= N0PAD * K0) return;
    int j = idx / K0, k = idx % K0;
    float v = 0.f;
    if (j < H_SZ) {
        if (k < IN_SZ)                      v = Wih[(size_t)j * IN_SZ + k];
        else if (k >= XK && k < XK + H_SZ)  v = Whh[(size_t)j * H_SZ + (k - XK)];
    }
    Wc[idx] = __float2bfloat16(v);
}

__global__ void pack_w1(const float* __restrict__ Wih, const float* __restrict__ Whh,
                        bf16* __restrict__ Wc) {
    int idx = blockIdx.x * blockDim.x + threadIdx.x;
    if (idx >= N1PAD * K1) return;
    int j = idx / K1, k = idx % K1;
    float v = 0.f;
    if (j < H_SZ) {
        if (k < H_SZ)                          v = Wih[(size_t)j * H_SZ + k];
        else if (k >= 672 && k < 672 + H_SZ)   v = Whh[(size_t)j * H_SZ + (k - 672)];
    }
    Wc[idx] = __float2bfloat16(v);
}

__global__ void pack_bias(const float* __restrict__ bi, const float* __restrict__ bh,
                          float* __restrict__ b, int n) {
    int j = blockIdx.x * blockDim.x + threadIdx.x;
    if (j >= n) return;
    b[j] = (j < H_SZ) ? (bi[j] + bh[j]) : 0.f;
}

// ---------------------------------------------------------------- persistent RNN
// r11 skeleton (tiles, W-in-LDS, agent write-through 2B stores, 17-slot ring,
// per-ring-wrap acquire fence) with WAVE-GRANULAR synchronization:
//   - strip s = wave id; producer wave computes rows s*16..s*16+15 only, and
//     consumer wave s reads exactly those rows -> flags are per (layer,rg,strip).
//   - after epilogue stores each wave drains ITS OWN vm queue
//     (s_waitcnt 0) and lane0 publishes a relaxed agent fetch_add; consumer
//     lane0 polls its strip flag (whole wave waits at reconvergence).
//   - NO __syncthreads in the loop: 8 strip-chains pipeline independently;
//     no wave waits on another strip's straggler or a block-wide drain.
// WAR guards per strip (identical ring arithmetic): writer at phase X polls
// readers of phase X-16; RAW polls imply the rest by per-block monotonicity.

__device__ __forceinline__ void tanh_store(ush* dst, float x) {
    x = fminf(fmaxf(x, -15.f), 15.f);
    float e = __expf(2.f * x);
    bf16 hb = __float2bfloat16((e - 1.f) / (e + 1.f));
    __hip_atomic_store(dst, *(ush*)&hb, __ATOMIC_RELAXED, __HIP_MEMORY_SCOPE_AGENT);
}

__device__ __forceinline__ void poll_ge(int* p, int need) {
    while (__hip_atomic_load(p, __ATOMIC_RELAXED, __HIP_MEMORY_SCOPE_AGENT) < need)
        __builtin_amdgcn_s_sleep(1);
}

__global__ __launch_bounds__(512, 2) void persist(
    const bf16* __restrict__ xs_pad, const bf16* __restrict__ Wc0,
    const bf16* __restrict__ Wc1, const float* __restrict__ b0,
    const float* __restrict__ b1, bf16* __restrict__ Sring,
    int* __restrict__ flags)
{
    extern __shared__ ush Wlds[];
    const int bid  = blockIdx.x;
    const int rg   = bid & 7;
    const int c8   = bid >> 3;
    const bool isL0 = (c8 < NL0B);
    const int tid  = threadIdx.x;
    const int wv   = tid >> 6;           // strip id
    const int lane = tid & 63;
    const int q8   = (lane >> 4) * 8;    // fragment k offset (elements)
    const int l15  = lane & 15;

    // ---- stage W slice into LDS in fragment order (once) ----
    if (isL0) {
        const int col0 = c8 * 96;
        for (int g = wv; g < 144; g += 8) {           // g = kc*6 + ct
            int kc = g / 6, ct = g % 6;
            const bf16* src = Wc0 + (size_t)(col0 + ct*16 + l15) * K0 + kc*32 + q8;
            *(uint4*)&Wlds[g*512 + lane*8] = *(const uint4*)src;
        }
    } else {
        const int col0 = (c8 - NL0B) * 48;
        for (int g = wv; g < 126; g += 8) {           // g = kc*3 + ct
            int kc = g / 3, ct = g % 3;
            const bf16* src = Wc1 + (size_t)(col0 + ct*16 + l15) * K1 + kc*32 + q8;
            *(uint4*)&Wlds[g*512 + lane*8] = *(const uint4*)src;
        }
    }
    __syncthreads();   // W read-only hereafter; last block-wide barrier

    const int loc = wv * 16 + l15;      // this wave's A-fragment row
    bf16* const ringbase = Sring + (size_t)rg * RING * SLAB;
    // per-strip flags: [(layer*8 + rg)*8 + strip] * FSTR
    int* const fL0s = flags + ((0*8 + rg)*8 + wv) * FSTR;   // NL0B publishers
    int* const fL1s = flags + ((1*8 + rg)*8 + wv) * FSTR;   // NL1B publishers

    if (isL0) {
        const int col0 = c8 * 96;
        float bias[6];
        #pragma unroll
        for (int ct = 0; ct < 6; ++ct) bias[ct] = b0[col0 + ct*16 + l15];

        for (int p = 0; p < 128; ++p) {
            const bf16* rsl = ringbase + (size_t)((p + RING - 1) % RING) * SLAB;
            bf16*       wsl = ringbase + (size_t)(p % RING) * SLAB;

            // xs chunks: input-static, issue before any wait
            const bf16* xr = xs_pad + ((size_t)p * B_SZ + rg*128 + loc) * XK + q8;
            uint4 xbuf[3];
            #pragma unroll
            for (int i = 0; i < 3; ++i) xbuf[i] = *(const uint4*)(xr + i*32);

            if (lane == 0) {
                if (p > 0)   poll_ge(&fL0s[p-1], NL0B);   // RAW: h0(p-1) strip
                if (p >= 17) poll_ge(&fL1s[p-16], NL1B);  // WAR: slot readers done
            }   // whole wave waits at reconvergence
            if (p >= RING + 1 && (p - 1) % RING == 0)
                __builtin_amdgcn_fence(__ATOMIC_ACQUIRE, "agent");

            const bf16* hr = rsl + (size_t)loc * K1 + q8;
            uint4 hbuf[21];
            #pragma unroll
            for (int i = 0; i < 21; ++i) hbuf[i] = *(const uint4*)(hr + i*32);

            f32x4 acc[6] = {};
            #pragma unroll
            for (int kc = 0; kc < 24; ++kc) {
                frag8 af = (kc < 3) ? *(const frag8*)&xbuf[kc]
                                    : *(const frag8*)&hbuf[kc-3];
                #pragma unroll
                for (int ct = 0; ct < 6; ++ct) {
                    frag8 wf = *(const frag8*)&Wlds[(kc*6+ct)*512 + lane*8];
                    acc[ct] = __builtin_amdgcn_mfma_f32_16x16x32_bf16(
                        af, wf, acc[ct], 0, 0, 0);
                }
            }
            const int rbase = wv*16 + (lane>>4)*4;
            #pragma unroll
            for (int ct = 0; ct < 6; ++ct) {
                const int col = col0 + ct*16 + l15;
                if (col < H_SZ) {
                    #pragma unroll
                    for (int i = 0; i < 4; ++i)
                        tanh_store((ush*)(wsl + (size_t)(rbase+i)*K1 + col),
                                   acc[ct][i] + bias[ct]);
                }
            }
            __builtin_amdgcn_s_waitcnt(0);   // wave-level drain of own stores
            if (lane == 0)
                __hip_atomic_fetch_add(&fL0s[p], 1, __ATOMIC_RELAXED,
                                       __HIP_MEMORY_SCOPE_AGENT);
        }
    } else {
        const int col0 = (c8 - NL0B) * 48;
        float bias[3];
        #pragma unroll
        for (int ct = 0; ct < 3; ++ct) bias[ct] = b1[col0 + ct*16 + l15];

        for (int q = 1; q <= 128; ++q) {
            const bf16* rsl = ringbase + (size_t)((q + RING - 1) % RING) * SLAB;
            bf16*       wsl = ringbase + (size_t)(q % RING) * SLAB;

            if (lane == 0) {
                poll_ge(&fL0s[q-1], NL0B);               // h0(q-1) strip ready
                if (q > 1) poll_ge(&fL1s[q-1], NL1B);    // h1(q-2) strip ready
            }
            if (q >= RING + 1 && (q - 1) % RING == 0)
                __builtin_amdgcn_fence(__ATOMIC_ACQUIRE, "agent");

            // A = slab row [h0(q-1) | h1(q-2)] (contiguous K=1344)
            const bf16* ar = rsl + (size_t)loc * K1 + q8;
            uint4 abuf[42];
            #pragma unroll
            for (int i = 0; i < 42; ++i) abuf[i] = *(const uint4*)(ar + i*32);
            f32x4 acc[3] = {};
            #pragma unroll
            for (int kc = 0; kc < 42; ++kc) {
                frag8 af = *(const frag8*)&abuf[kc];
                #pragma unroll
                for (int ct = 0; ct < 3; ++ct) {
                    frag8 wf = *(const frag8*)&Wlds[(kc*3+ct)*512 + lane*8];
                    acc[ct] = __builtin_amdgcn_mfma_f32_16x16x32_bf16(
                        af, wf, acc[ct], 0, 0, 0);
                }
            }
            const int rbase = wv*16 + (lane>>4)*4;
            #pragma unroll
            for (int ct = 0; ct < 3; ++ct) {
                const int col = col0 + ct*16 + l15;
                if (col < H_SZ) {
                    #pragma unroll
                    for (int i = 0; i < 4; ++i)
                        tanh_store((ush*)(wsl + (size_t)(rbase+i)*K1 + 672 + col),
                                   acc[ct][i] + bias[ct]);
                }
            }
            __builtin_amdgcn_s_waitcnt(0);   // wave-level drain of own stores
            if (lane == 0)
                __hip_atomic_fetch_add(&fL1s[q], 1, __ATOMIC_RELAXED,
                                       __HIP_MEMORY_SCOPE_AGENT);
        }
    }
}

// ---------------------------------------------------------------- classifier
__global__ __launch_bounds__(256) void classifier(
    const bf16* __restrict__ Sring, const float* __restrict__ Wout,
    const float* __restrict__ bout, float* __restrict__ out)
{
    const int wave = threadIdx.x >> 6, lane = threadIdx.x & 63;
    const int row = blockIdx.x * 4 + wave;
    const int rg = row >> 7, loc = row & 127;
    const bf16* h1 = Sring + ((size_t)rg * RING + (128 % RING)) * SLAB
                     + (size_t)loc * K1 + 672;
    float acc[OUT_SZ] = {0.f, 0.f, 0.f, 0.f, 0.f};
    for (int k = lane; k < H_SZ; k += 64) {
        float h = __bfloat162float(h1[k]);
        #pragma unroll
        for (int o = 0; o < OUT_SZ; ++o) acc[o] += h * Wout[(size_t)o * H_SZ + k];
    }
    #pragma unroll
    for (int o = 0; o < OUT_SZ; ++o) {
        float v = acc[o];
        #pragma unroll
        for (int off = 32; off; off >>= 1) v += __shfl_down(v, off, 64);
        if (lane == 0) out[(size_t)row * OUT_SZ + o] = v + bout[o];
    }
}

// ---------------------------------------------------------------- launch

extern "C" void kernel_launch(void* const* d_in, const int* in_sizes, int n_in,
                              void* d_out, int out_size, void* d_ws, size_t ws_size,
                              hipStream_t stream) {
    const float* xs   = (const float*)d_in[0];
    const float* Wih0 = (const float*)d_in[1];
    const float* Whh0 = (const float*)d_in[2];
    const float* bih0 = (const float*)d_in[3];
    const float* bhh0 = (const float*)d_in[4];
    const float* Wih1 = (const float*)d_in[5];
    const float* Whh1 = (const float*)d_in[6];
    const float* bih1 = (const float*)d_in[7];
    const float* bhh1 = (const float*)d_in[8];
    const float* Wout = (const float*)d_in[9];
    const float* bout = (const float*)d_in[10];
    float* out = (float*)d_out;

    char* ws = (char*)d_ws;
    size_t off = 0;
    bf16* xs_pad = (bf16*)(ws + off); off += (size_t)T_STEPS * B_SZ * XK * 2;
    bf16* Wc0    = (bf16*)(ws + off); off += (size_t)N0PAD * K0 * 2;
    bf16* Wc1    = (bf16*)(ws + off); off += (size_t)N1PAD * K1 * 2;
    float* b0    = (float*)(ws + off); off += (size_t)N0PAD * 4;
    float* b1    = (float*)(ws + off); off += (size_t)N1PAD * 4;
    bf16* Sring  = (bf16*)(ws + off); off += (size_t)8 * RING * SLAB * 2;
    int*  flags  = (int*)(ws + off);  off += (size_t)128 * FSTR * 4;

    // ring (incl. zero-state slots + pad columns) and all flag arrays start zero
    hipMemsetAsync(Sring, 0, (size_t)8 * RING * SLAB * 2, stream);
    hipMemsetAsync(flags, 0, (size_t)128 * FSTR * 4, stream);

    prep_xs <<<(T_STEPS * B_SZ * XK + 255) / 256, 256, 0, stream>>>(xs, xs_pad);
    pack_w0 <<<(N0PAD * K0 + 255) / 256, 256, 0, stream>>>(Wih0, Whh0, Wc0);
    pack_w1 <<<(N1PAD * K1 + 255) / 256, 256, 0, stream>>>(Wih1, Whh1, Wc1);
    pack_bias<<<(N0PAD + 255) / 256, 256, 0, stream>>>(bih0, bhh0, b0, N0PAD);
    pack_bias<<<(N1PAD + 255) / 256, 256, 0, stream>>>(bih1, bhh1, b1, N1PAD);

    // dynamic LDS: max(W0 slice 147456 B, W1 slice 129024 B)
    hipFuncSetAttribute((const void*)persist,
                        hipFuncAttributeMaxDynamicSharedMemorySize, 147456);
    void* args[] = { (void*)&xs_pad, (void*)&Wc0, (void*)&Wc1, (void*)&b0,
                     (void*)&b1, (void*)&Sring, (void*)&flags };
    hipLaunchCooperativeKernel((const void*)persist, dim3(NBLK), dim3(512),
                               args, 147456, stream);

    classifier<<<B_SZ / 4, 256, 0, stream>>>(Sring, Wout, bout, out);
}

// Round 13
// 1645.119 us; speedup vs baseline: 1.0679x; 1.0679x over previous
//
#include <hip/hip_runtime.h>
#include <hip/hip_bf16.h>

#define T_STEPS 128
#define B_SZ    1024
#define IN_SZ   47
#define H_SZ    646
#define OUT_SZ  5

#define XK    96      // xs padded row stride (47 -> 96)
#define K0    768     // layer0 K = 96 + 672
#define K1    1344    // layer1 K = 672 + 672 (also the state-slab row stride)
#define N0PAD 704     // L0 packed-W cols (11 * 64, zero-padded)
#define N1PAD 672     // L1 packed-W cols
#define RING  17      // state ring slots per row-group (fresh-address coherence)
#define SLAB  172032  // 128 rows * 1344 cols, elements per rg slab
#define FSTR  160     // flag array stride (ints), 640 B -> no cross-line sharing

// tiles (r11-proven): L0 96-col x7 blocks, L1 48-col x14 blocks
#define NL0B  7
#define NL1B  14
#define NBLK  (8 * (NL0B + NL1B))   // 168

typedef __hip_bfloat16 bf16;
typedef unsigned short ush;
using frag8 = __attribute__((ext_vector_type(8))) short;  // 8 bf16
using f32x4 = __attribute__((ext_vector_type(4))) float;

// ---------------------------------------------------------------- prep kernels

__global__ void prep_xs(const float* __restrict__ xs, bf16* __restrict__ xs_pad) {
    int idx = blockIdx.x * blockDim.x + threadIdx.x;
    if (idx >= T_STEPS * B_SZ * XK) return;
    int k = idx % XK;
    int rb = idx / XK;
    float v = (k < IN_SZ) ? xs[(size_t)rb * IN_SZ + k] : 0.f;
    xs_pad[idx] = __float2bfloat16(v);
}

__global__ void pack_w0(const float* __restrict__ Wih, const float* __restrict__ Whh,
                        bf16* __restrict__ Wc) {
    int idx = blockIdx.x * blockDim.x + threadIdx.x;
    if (idx >= N0PAD * K0) return;
    int j = idx / K0, k = idx % K0;
    float v = 0.f;
    if (j < H_SZ) {
        if (k < IN_SZ)                      v = Wih[(size_t)j * IN_SZ + k];
        else if (k >= XK && k < XK + H_SZ)  v = Whh[(size_t)j * H_SZ + (k - XK)];
    }
    Wc[idx] = __float2bfloat16(v);
}

__global__ void pack_w1(const float* __restrict__ Wih, const float* __restrict__ Whh,
                        bf16* __restrict__ Wc) {
    int idx = blockIdx.x * blockDim.x + threadIdx.x;
    if (idx >= N1PAD * K1) return;
    int j = idx / K1, k = idx % K1;
    float v = 0.f;
    if (j < H_SZ) {
        if (k < H_SZ)                          v = Wih[(size_t)j * H_SZ + k];
        else if (k >= 672 && k < 672 + H_SZ)   v = Whh[(size_t)j * H_SZ + (k - 672)];
    }
    Wc[idx] = __float2bfloat16(v);
}

__global__ void pack_bias(const float* __restrict__ bi, const float* __restrict__ bh,
                          float* __restrict__ b, int n) {
    int j = blockIdx.x * blockDim.x + threadIdx.x;
    if (j >= n) return;
    b[j] = (j < H_SZ) ? (bi[j] + bh[j]) : 0.f;
}

// ---------------------------------------------------------------- persistent RNN
// r11 skeleton, single change: epilogue h-state stores are PLAIN coalesced
// stores (dirty in the producer XCD's L2) instead of agent write-through.
// Rationale: producers and consumers of a row-group share rg = bid&7, and
// consecutive blockIds round-robin across the 8 XCDs -> rg is XCD-co-located,
// so dirty-L2 data is directly visible to all its consumers. Ordering: the
// per-wave vmcnt(0) drain at the epilogue __syncthreads retires stores into
// L2 BEFORE thread0's relaxed agent flag-add publishes; consumers poll with
// agent loads (L1-bypassing), read fresh ring addresses (17 slots), and run
// one agent-acquire fence per ring wrap to clear recycled-address L1 lines.
// If the rg<->XCD assumption is wrong, reads go stale and the harness absmax
// check fails loudly (r5 already proved plain-store content is otherwise
// correct). Poll backoff s_sleep(16) cuts the poll-contention term seen in
// r10/r12. End-of-kernel implicit release makes the final state visible to
// the classifier kernel.

__device__ __forceinline__ void tanh_store(ush* dst, float x) {
    x = fminf(fmaxf(x, -15.f), 15.f);
    float e = __expf(2.f * x);
    bf16 hb = __float2bfloat16((e - 1.f) / (e + 1.f));
    *dst = *(ush*)&hb;     // plain store: coalesced, dirty in local (XCD) L2
}

__device__ __forceinline__ void poll_ge(int* p, int need) {
    while (__hip_atomic_load(p, __ATOMIC_RELAXED, __HIP_MEMORY_SCOPE_AGENT) < need)
        __builtin_amdgcn_s_sleep(16);
}

__global__ __launch_bounds__(512, 2) void persist(
    const bf16* __restrict__ xs_pad, const bf16* __restrict__ Wc0,
    const bf16* __restrict__ Wc1, const float* __restrict__ b0,
    const float* __restrict__ b1, bf16* __restrict__ Sring,
    int* __restrict__ flags)
{
    extern __shared__ ush Wlds[];
    const int bid  = blockIdx.x;
    const int rg   = bid & 7;
    const int c8   = bid >> 3;
    const bool isL0 = (c8 < NL0B);
    const int tid  = threadIdx.x;
    const int wv   = tid >> 6;
    const int lane = tid & 63;
    const int q8   = (lane >> 4) * 8;    // fragment k offset (elements)
    const int l15  = lane & 15;

    // ---- stage W slice into LDS in fragment order (once) ----
    if (isL0) {
        const int col0 = c8 * 96;
        for (int g = wv; g < 144; g += 8) {           // g = kc*6 + ct
            int kc = g / 6, ct = g % 6;
            const bf16* src = Wc0 + (size_t)(col0 + ct*16 + l15) * K0 + kc*32 + q8;
            *(uint4*)&Wlds[g*512 + lane*8] = *(const uint4*)src;
        }
    } else {
        const int col0 = (c8 - NL0B) * 48;
        for (int g = wv; g < 126; g += 8) {           // g = kc*3 + ct
            int kc = g / 3, ct = g % 3;
            const bf16* src = Wc1 + (size_t)(col0 + ct*16 + l15) * K1 + kc*32 + q8;
            *(uint4*)&Wlds[g*512 + lane*8] = *(const uint4*)src;
        }
    }
    __syncthreads();

    const int loc = wv * 16 + l15;      // this wave's A-fragment row (16 rows/wave)
    bf16* const ringbase = Sring + (size_t)rg * RING * SLAB;
    int*  const fL0 = flags + rg * FSTR;          // NL0B publishers
    int*  const fL1 = flags + (8 + rg) * FSTR;    // NL1B publishers

    if (isL0) {
        const int col0 = c8 * 96;
        float bias[6];
        #pragma unroll
        for (int ct = 0; ct < 6; ++ct) bias[ct] = b0[col0 + ct*16 + l15];

        for (int p = 0; p < 128; ++p) {
            if (tid == 0) {
                if (p > 0)   poll_ge(&fL0[p-1], NL0B);
                if (p >= 17) poll_ge(&fL1[p-16], NL1B);  // WAR: slot p%17 readers done
            }
            __syncthreads();
            if (p >= RING + 1 && (p - 1) % RING == 0)
                __builtin_amdgcn_fence(__ATOMIC_ACQUIRE, "agent");
            const bf16* rsl = ringbase + (size_t)((p + RING - 1) % RING) * SLAB;
            bf16*       wsl = ringbase + (size_t)(p % RING) * SLAB;

            // A = [x_t(96) | h0(p-1)(672)], C = h0(p) -> slab cols [0,672)
            const bf16* xr = xs_pad + ((size_t)p * B_SZ + rg*128 + loc) * XK + q8;
            const bf16* hr = rsl + (size_t)loc * K1 + q8;
            uint4 abuf[24];
            #pragma unroll
            for (int i = 0; i < 24; ++i)
                abuf[i] = (i < 3) ? *(const uint4*)(xr + i*32)
                                  : *(const uint4*)(hr + (i-3)*32);
            f32x4 acc[6] = {};
            #pragma unroll
            for (int kc = 0; kc < 24; ++kc) {
                frag8 af = *(const frag8*)&abuf[kc];
                #pragma unroll
                for (int ct = 0; ct < 6; ++ct) {
                    frag8 wf = *(const frag8*)&Wlds[(kc*6+ct)*512 + lane*8];
                    acc[ct] = __builtin_amdgcn_mfma_f32_16x16x32_bf16(
                        af, wf, acc[ct], 0, 0, 0);
                }
            }
            const int rbase = wv*16 + (lane>>4)*4;
            #pragma unroll
            for (int ct = 0; ct < 6; ++ct) {
                const int col = col0 + ct*16 + l15;
                if (col < H_SZ) {
                    #pragma unroll
                    for (int i = 0; i < 4; ++i)
                        tanh_store((ush*)(wsl + (size_t)(rbase+i)*K1 + col),
                                   acc[ct][i] + bias[ct]);
                }
            }
            __syncthreads();   // per-wave vmcnt(0) drain: stores in L2 pre-publish
            if (tid == 0)
                __hip_atomic_fetch_add(&fL0[p], 1, __ATOMIC_RELAXED,
                                       __HIP_MEMORY_SCOPE_AGENT);
        }
    } else {
        const int col0 = (c8 - NL0B) * 48;
        float bias[3];
        #pragma unroll
        for (int ct = 0; ct < 3; ++ct) bias[ct] = b1[col0 + ct*16 + l15];

        for (int q = 1; q <= 128; ++q) {
            if (tid == 0) {
                poll_ge(&fL0[q-1], NL0B);               // h0(q-1) ready
                if (q > 1) poll_ge(&fL1[q-1], NL1B);    // h1(q-2) ready
            }
            __syncthreads();
            if (q >= RING + 1 && (q - 1) % RING == 0)
                __builtin_amdgcn_fence(__ATOMIC_ACQUIRE, "agent");
            const bf16* rsl = ringbase + (size_t)((q + RING - 1) % RING) * SLAB;
            bf16*       wsl = ringbase + (size_t)(q % RING) * SLAB;

            // A = slab row [h0(q-1) | h1(q-2)] (contiguous K=1344)
            const bf16* ar = rsl + (size_t)loc * K1 + q8;
            uint4 abuf[42];
            #pragma unroll
            for (int i = 0; i < 42; ++i) abuf[i] = *(const uint4*)(ar + i*32);
            f32x4 acc[3] = {};
            #pragma unroll
            for (int kc = 0; kc < 42; ++kc) {
                frag8 af = *(const frag8*)&abuf[kc];
                #pragma unroll
                for (int ct = 0; ct < 3; ++ct) {
                    frag8 wf = *(const frag8*)&Wlds[(kc*3+ct)*512 + lane*8];
                    acc[ct] = __builtin_amdgcn_mfma_f32_16x16x32_bf16(
                        af, wf, acc[ct], 0, 0, 0);
                }
            }
            const int rbase = wv*16 + (lane>>4)*4;
            #pragma unroll
            for (int ct = 0; ct < 3; ++ct) {
                const int col = col0 + ct*16 + l15;
                if (col < H_SZ) {
                    #pragma unroll
                    for (int i = 0; i < 4; ++i)
                        tanh_store((ush*)(wsl + (size_t)(rbase+i)*K1 + 672 + col),
                                   acc[ct][i] + bias[ct]);
                }
            }
            __syncthreads();   // per-wave vmcnt(0) drain: stores in L2 pre-publish
            if (tid == 0)
                __hip_atomic_fetch_add(&fL1[q], 1, __ATOMIC_RELAXED,
                                       __HIP_MEMORY_SCOPE_AGENT);
        }
    }
}

// ---------------------------------------------------------------- classifier
__global__ __launch_bounds__(256) void classifier(
    const bf16* __restrict__ Sring, const float* __restrict__ Wout,
    const float* __restrict__ bout, float* __restrict__ out)
{
    const int wave = threadIdx.x >> 6, lane = threadIdx.x & 63;
    const int row = blockIdx.x * 4 + wave;
    const int rg = row >> 7, loc = row & 127;
    const bf16* h1 = Sring + ((size_t)rg * RING + (128 % RING)) * SLAB
                     + (size_t)loc * K1 + 672;
    float acc[OUT_SZ] = {0.f, 0.f, 0.f, 0.f, 0.f};
    for (int k = lane; k < H_SZ; k += 64) {
        float h = __bfloat162float(h1[k]);
        #pragma unroll
        for (int o = 0; o < OUT_SZ; ++o) acc[o] += h * Wout[(size_t)o * H_SZ + k];
    }
    #pragma unroll
    for (int o = 0; o < OUT_SZ; ++o) {
        float v = acc[o];
        #pragma unroll
        for (int off = 32; off; off >>= 1) v += __shfl_down(v, off, 64);
        if (lane == 0) out[(size_t)row * OUT_SZ + o] = v + bout[o];
    }
}

// ---------------------------------------------------------------- launch

extern "C" void kernel_launch(void* const* d_in, const int* in_sizes, int n_in,
                              void* d_out, int out_size, void* d_ws, size_t ws_size,
                              hipStream_t stream) {
    const float* xs   = (const float*)d_in[0];
    const float* Wih0 = (const float*)d_in[1];
    const float* Whh0 = (const float*)d_in[2];
    const float* bih0 = (const float*)d_in[3];
    const float* bhh0 = (const float*)d_in[4];
    const float* Wih1 = (const float*)d_in[5];
    const float* Whh1 = (const float*)d_in[6];
    const float* bih1 = (const float*)d_in[7];
    const float* bhh1 = (const float*)d_in[8];
    const float* Wout = (const float*)d_in[9];
    const float* bout = (const float*)d_in[10];
    float* out = (float*)d_out;

    char* ws = (char*)d_ws;
    size_t off = 0;
    bf16* xs_pad = (bf16*)(ws + off); off += (size_t)T_STEPS * B_SZ * XK * 2;
    bf16* Wc0    = (bf16*)(ws + off); off += (size_t)N0PAD * K0 * 2;
    bf16* Wc1    = (bf16*)(ws + off); off += (size_t)N1PAD * K1 * 2;
    float* b0    = (float*)(ws + off); off += (size_t)N0PAD * 4;
    float* b1    = (float*)(ws + off); off += (size_t)N1PAD * 4;
    bf16* Sring  = (bf16*)(ws + off); off += (size_t)8 * RING * SLAB * 2;
    int*  flags  = (int*)(ws + off);  off += (size_t)16 * FSTR * 4;

    // ring (incl. zero-state slots + pad columns) and both flag arrays start zero
    hipMemsetAsync(Sring, 0, (size_t)8 * RING * SLAB * 2, stream);
    hipMemsetAsync(flags, 0, (size_t)16 * FSTR * 4, stream);

    prep_xs <<<(T_STEPS * B_SZ * XK + 255) / 256, 256, 0, stream>>>(xs, xs_pad);
    pack_w0 <<<(N0PAD * K0 + 255) / 256, 256, 0, stream>>>(Wih0, Whh0, Wc0);
    pack_w1 <<<(N1PAD * K1 + 255) / 256, 256, 0, stream>>>(Wih1, Whh1, Wc1);
    pack_bias<<<(N0PAD + 255) / 256, 256, 0, stream>>>(bih0, bhh0, b0, N0PAD);
    pack_bias<<<(N1PAD + 255) / 256, 256, 0, stream>>>(bih1, bhh1, b1, N1PAD);

    // dynamic LDS: max(W0 slice 147456 B, W1 slice 129024 B)
    hipFuncSetAttribute((const void*)persist,
                        hipFuncAttributeMaxDynamicSharedMemorySize, 147456);
    void* args[] = { (void*)&xs_pad, (void*)&Wc0, (void*)&Wc1, (void*)&b0,
                     (void*)&b1, (void*)&Sring, (void*)&flags };
    hipLaunchCooperativeKernel((const void*)persist, dim3(NBLK), dim3(512),
                               args, 147456, stream);

    classifier<<<B_SZ / 4, 256, 0, stream>>>(Sring, Wout, bout, out);
}

// Round 14
// 1620.332 us; speedup vs baseline: 1.0842x; 1.0153x over previous
//
#include <hip/hip_runtime.h>
#include <hip/hip_bf16.h>

#define T_STEPS 128
#define B_SZ    1024
#define IN_SZ   47
#define H_SZ    646
#define OUT_SZ  5

#define XK    96      // xs padded row stride (47 -> 96)
#define K0    768     // layer0 K = 96 + 672
#define K1    1344    // layer1 K = 672 + 672 (also the state-slab row stride)
#define N0PAD 704     // L0 packed-W cols (11 * 64, zero-padded)
#define N1PAD 672     // L1 packed-W cols
#define RING  17      // state ring slots per row-group (fresh-address coherence)
#define SLAB  172032  // 128 rows * 1344 cols, elements per rg slab
#define FSTR  160     // flag array stride (ints), 640 B -> no cross-line sharing

// tiles (r11-proven): L0 96-col x7 blocks, L1 48-col x14 blocks
#define NL0B  7
#define NL1B  14
#define NBLK  (8 * (NL0B + NL1B))   // 168

typedef __hip_bfloat16 bf16;
typedef unsigned short ush;
using frag8 = __attribute__((ext_vector_type(8))) short;  // 8 bf16
using f32x4 = __attribute__((ext_vector_type(4))) float;

// ---------------------------------------------------------------- prep kernels

__global__ void prep_xs(const float* __restrict__ xs, bf16* __restrict__ xs_pad) {
    int idx = blockIdx.x * blockDim.x + threadIdx.x;
    if (idx >= T_STEPS * B_SZ * XK) return;
    int k = idx % XK;
    int rb = idx / XK;
    float v = (k < IN_SZ) ? xs[(size_t)rb * IN_SZ + k] : 0.f;
    xs_pad[idx] = __float2bfloat16(v);
}

__global__ void pack_w0(const float* __restrict__ Wih, const float* __restrict__ Whh,
                        bf16* __restrict__ Wc) {
    int idx = blockIdx.x * blockDim.x + threadIdx.x;
    if (idx >= N0PAD * K0) return;
    int j = idx / K0, k = idx % K0;
    float v = 0.f;
    if (j < H_SZ) {
        if (k < IN_SZ)                      v = Wih[(size_t)j * IN_SZ + k];
        else if (k >= XK && k < XK + H_SZ)  v = Whh[(size_t)j * H_SZ + (k - XK)];
    }
    Wc[idx] = __float2bfloat16(v);
}

__global__ void pack_w1(const float* __restrict__ Wih, const float* __restrict__ Whh,
                        bf16* __restrict__ Wc) {
    int idx = blockIdx.x * blockDim.x + threadIdx.x;
    if (idx >= N1PAD * K1) return;
    int j = idx / K1, k = idx % K1;
    float v = 0.f;
    if (j < H_SZ) {
        if (k < H_SZ)                          v = Wih[(size_t)j * H_SZ + k];
        else if (k >= 672 && k < 672 + H_SZ)   v = Whh[(size_t)j * H_SZ + (k - 672)];
    }
    Wc[idx] = __float2bfloat16(v);
}

__global__ void pack_bias(const float* __restrict__ bi, const float* __restrict__ bh,
                          float* __restrict__ b, int n) {
    int j = blockIdx.x * blockDim.x + threadIdx.x;
    if (j >= n) return;
    b[j] = (j < H_SZ) ? (bi[j] + bh[j]) : 0.f;
}

// ---------------------------------------------------------------- persistent RNN
// r13 skeleton (tiles, W-in-LDS, PLAIN dirty-L2 h-state stores with rg<->XCD
// co-location — r13-validated; 17-slot ring; per-wrap agent-acquire fence;
// aggregate flags, thread0 poll + __syncthreads; publish after per-wave
// vmcnt(0) drain). New vs r13 — CRITICAL-PATH REORDER inside the L1 phase:
//   the h0-half of A (K-chunks 0..20) depends only on fL0[q-1], which L0's
//   15-phase lead makes a no-wait; so L1 polls fL0, loads + accumulates the
//   h0 half FIRST, and only then polls fL1[q-1] (the true serial gate) and
//   loads the h1 half. The L1(q)->L1(q+1) serial link shrinks from the full
//   phase to [poll + 21 chunks + 63 MFMA + epilogue + drain].
// L0 keeps xs-loads hoisted before its poll. Poll sleep 16 -> 2.

__device__ __forceinline__ void tanh_store(ush* dst, float x) {
    x = fminf(fmaxf(x, -15.f), 15.f);
    float e = __expf(2.f * x);
    bf16 hb = __float2bfloat16((e - 1.f) / (e + 1.f));
    *dst = *(ush*)&hb;     // plain store: coalesced, dirty in local (XCD) L2
}

__device__ __forceinline__ void poll_ge(int* p, int need) {
    while (__hip_atomic_load(p, __ATOMIC_RELAXED, __HIP_MEMORY_SCOPE_AGENT) < need)
        __builtin_amdgcn_s_sleep(2);
}

__global__ __launch_bounds__(512, 2) void persist(
    const bf16* __restrict__ xs_pad, const bf16* __restrict__ Wc0,
    const bf16* __restrict__ Wc1, const float* __restrict__ b0,
    const float* __restrict__ b1, bf16* __restrict__ Sring,
    int* __restrict__ flags)
{
    extern __shared__ ush Wlds[];
    const int bid  = blockIdx.x;
    const int rg   = bid & 7;
    const int c8   = bid >> 3;
    const bool isL0 = (c8 < NL0B);
    const int tid  = threadIdx.x;
    const int wv   = tid >> 6;
    const int lane = tid & 63;
    const int q8   = (lane >> 4) * 8;    // fragment k offset (elements)
    const int l15  = lane & 15;

    // ---- stage W slice into LDS in fragment order (once) ----
    if (isL0) {
        const int col0 = c8 * 96;
        for (int g = wv; g < 144; g += 8) {           // g = kc*6 + ct
            int kc = g / 6, ct = g % 6;
            const bf16* src = Wc0 + (size_t)(col0 + ct*16 + l15) * K0 + kc*32 + q8;
            *(uint4*)&Wlds[g*512 + lane*8] = *(const uint4*)src;
        }
    } else {
        const int col0 = (c8 - NL0B) * 48;
        for (int g = wv; g < 126; g += 8) {           // g = kc*3 + ct
            int kc = g / 3, ct = g % 3;
            const bf16* src = Wc1 + (size_t)(col0 + ct*16 + l15) * K1 + kc*32 + q8;
            *(uint4*)&Wlds[g*512 + lane*8] = *(const uint4*)src;
        }
    }
    __syncthreads();

    const int loc = wv * 16 + l15;      // this wave's A-fragment row (16 rows/wave)
    bf16* const ringbase = Sring + (size_t)rg * RING * SLAB;
    int*  const fL0 = flags + rg * FSTR;          // NL0B publishers
    int*  const fL1 = flags + (8 + rg) * FSTR;    // NL1B publishers

    if (isL0) {
        const int col0 = c8 * 96;
        float bias[6];
        #pragma unroll
        for (int ct = 0; ct < 6; ++ct) bias[ct] = b0[col0 + ct*16 + l15];

        for (int p = 0; p < 128; ++p) {
            const bf16* rsl = ringbase + (size_t)((p + RING - 1) % RING) * SLAB;
            bf16*       wsl = ringbase + (size_t)(p % RING) * SLAB;

            // xs chunks: input-static, issue before any wait
            const bf16* xr = xs_pad + ((size_t)p * B_SZ + rg*128 + loc) * XK + q8;
            uint4 xbuf[3];
            #pragma unroll
            for (int i = 0; i < 3; ++i) xbuf[i] = *(const uint4*)(xr + i*32);

            if (tid == 0) {
                if (p > 0)   poll_ge(&fL0[p-1], NL0B);
                if (p >= 17) poll_ge(&fL1[p-16], NL1B);  // WAR: slot p%17 readers done
            }
            __syncthreads();
            if (p >= RING + 1 && (p - 1) % RING == 0)
                __builtin_amdgcn_fence(__ATOMIC_ACQUIRE, "agent");

            // A = [x_t(96) | h0(p-1)(672)], C = h0(p) -> slab cols [0,672)
            const bf16* hr = rsl + (size_t)loc * K1 + q8;
            uint4 hbuf[21];
            #pragma unroll
            for (int i = 0; i < 21; ++i) hbuf[i] = *(const uint4*)(hr + i*32);

            f32x4 acc[6] = {};
            #pragma unroll
            for (int kc = 0; kc < 24; ++kc) {
                frag8 af = (kc < 3) ? *(const frag8*)&xbuf[kc]
                                    : *(const frag8*)&hbuf[kc-3];
                #pragma unroll
                for (int ct = 0; ct < 6; ++ct) {
                    frag8 wf = *(const frag8*)&Wlds[(kc*6+ct)*512 + lane*8];
                    acc[ct] = __builtin_amdgcn_mfma_f32_16x16x32_bf16(
                        af, wf, acc[ct], 0, 0, 0);
                }
            }
            const int rbase = wv*16 + (lane>>4)*4;
            #pragma unroll
            for (int ct = 0; ct < 6; ++ct) {
                const int col = col0 + ct*16 + l15;
                if (col < H_SZ) {
                    #pragma unroll
                    for (int i = 0; i < 4; ++i)
                        tanh_store((ush*)(wsl + (size_t)(rbase+i)*K1 + col),
                                   acc[ct][i] + bias[ct]);
                }
            }
            __syncthreads();   // per-wave vmcnt(0) drain: stores in L2 pre-publish
            if (tid == 0)
                __hip_atomic_fetch_add(&fL0[p], 1, __ATOMIC_RELAXED,
                                       __HIP_MEMORY_SCOPE_AGENT);
        }
    } else {
        const int col0 = (c8 - NL0B) * 48;
        float bias[3];
        #pragma unroll
        for (int ct = 0; ct < 3; ++ct) bias[ct] = b1[col0 + ct*16 + l15];

        for (int q = 1; q <= 128; ++q) {
            const bf16* rsl = ringbase + (size_t)((q + RING - 1) % RING) * SLAB;
            bf16*       wsl = ringbase + (size_t)(q % RING) * SLAB;
            const bf16* ar  = rsl + (size_t)loc * K1 + q8;

            // ---- stage 1: h0 half (gated only by fL0; L0 runs ~15 ahead) ----
            if (tid == 0) poll_ge(&fL0[q-1], NL0B);
            __syncthreads();
            if (q >= RING + 1 && (q - 1) % RING == 0)
                __builtin_amdgcn_fence(__ATOMIC_ACQUIRE, "agent");

            uint4 h0buf[21];
            #pragma unroll
            for (int i = 0; i < 21; ++i) h0buf[i] = *(const uint4*)(ar + i*32);
            f32x4 acc[3] = {};
            #pragma unroll
            for (int kc = 0; kc < 21; ++kc) {
                frag8 af = *(const frag8*)&h0buf[kc];
                #pragma unroll
                for (int ct = 0; ct < 3; ++ct) {
                    frag8 wf = *(const frag8*)&Wlds[(kc*3+ct)*512 + lane*8];
                    acc[ct] = __builtin_amdgcn_mfma_f32_16x16x32_bf16(
                        af, wf, acc[ct], 0, 0, 0);
                }
            }

            // ---- stage 2: h1 half (the true serial gate, polled LATE) ----
            if (q > 1) {
                if (tid == 0) poll_ge(&fL1[q-1], NL1B);
                __syncthreads();
            }
            uint4 h1buf[21];
            #pragma unroll
            for (int i = 0; i < 21; ++i)
                h1buf[i] = *(const uint4*)(ar + (21 + i)*32);
            #pragma unroll
            for (int kc = 21; kc < 42; ++kc) {
                frag8 af = *(const frag8*)&h1buf[kc-21];
                #pragma unroll
                for (int ct = 0; ct < 3; ++ct) {
                    frag8 wf = *(const frag8*)&Wlds[(kc*3+ct)*512 + lane*8];
                    acc[ct] = __builtin_amdgcn_mfma_f32_16x16x32_bf16(
                        af, wf, acc[ct], 0, 0, 0);
                }
            }
            const int rbase = wv*16 + (lane>>4)*4;
            #pragma unroll
            for (int ct = 0; ct < 3; ++ct) {
                const int col = col0 + ct*16 + l15;
                if (col < H_SZ) {
                    #pragma unroll
                    for (int i = 0; i < 4; ++i)
                        tanh_store((ush*)(wsl + (size_t)(rbase+i)*K1 + 672 + col),
                                   acc[ct][i] + bias[ct]);
                }
            }
            __syncthreads();   // per-wave vmcnt(0) drain: stores in L2 pre-publish
            if (tid == 0)
                __hip_atomic_fetch_add(&fL1[q], 1, __ATOMIC_RELAXED,
                                       __HIP_MEMORY_SCOPE_AGENT);
        }
    }
}

// ---------------------------------------------------------------- classifier
__global__ __launch_bounds__(256) void classifier(
    const bf16* __restrict__ Sring, const float* __restrict__ Wout,
    const float* __restrict__ bout, float* __restrict__ out)
{
    const int wave = threadIdx.x >> 6, lane = threadIdx.x & 63;
    const int row = blockIdx.x * 4 + wave;
    const int rg = row >> 7, loc = row & 127;
    const bf16* h1 = Sring + ((size_t)rg * RING + (128 % RING)) * SLAB
                     + (size_t)loc * K1 + 672;
    float acc[OUT_SZ] = {0.f, 0.f, 0.f, 0.f, 0.f};
    for (int k = lane; k < H_SZ; k += 64) {
        float h = __bfloat162float(h1[k]);
        #pragma unroll
        for (int o = 0; o < OUT_SZ; ++o) acc[o] += h * Wout[(size_t)o * H_SZ + k];
    }
    #pragma unroll
    for (int o = 0; o < OUT_SZ; ++o) {
        float v = acc[o];
        #pragma unroll
        for (int off = 32; off; off >>= 1) v += __shfl_down(v, off, 64);
        if (lane == 0) out[(size_t)row * OUT_SZ + o] = v + bout[o];
    }
}

// ---------------------------------------------------------------- launch

extern "C" void kernel_launch(void* const* d_in, const int* in_sizes, int n_in,
                              void* d_out, int out_size, void* d_ws, size_t ws_size,
                              hipStream_t stream) {
    const float* xs   = (const float*)d_in[0];
    const float* Wih0 = (const float*)d_in[1];
    const float* Whh0 = (const float*)d_in[2];
    const float* bih0 = (const float*)d_in[3];
    const float* bhh0 = (const float*)d_in[4];
    const float* Wih1 = (const float*)d_in[5];
    const float* Whh1 = (const float*)d_in[6];
    const float* bih1 = (const float*)d_in[7];
    const float* bhh1 = (const float*)d_in[8];
    const float* Wout = (const float*)d_in[9];
    const float* bout = (const float*)d_in[10];
    float* out = (float*)d_out;

    char* ws = (char*)d_ws;
    size_t off = 0;
    bf16* xs_pad = (bf16*)(ws + off); off += (size_t)T_STEPS * B_SZ * XK * 2;
    bf16* Wc0    = (bf16*)(ws + off); off += (size_t)N0PAD * K0 * 2;
    bf16* Wc1    = (bf16*)(ws + off); off += (size_t)N1PAD * K1 * 2;
    float* b0    = (float*)(ws + off); off += (size_t)N0PAD * 4;
    float* b1    = (float*)(ws + off); off += (size_t)N1PAD * 4;
    bf16* Sring  = (bf16*)(ws + off); off += (size_t)8 * RING * SLAB * 2;
    int*  flags  = (int*)(ws + off);  off += (size_t)16 * FSTR * 4;

    // ring (incl. zero-state slots + pad columns) and both flag arrays start zero
    hipMemsetAsync(Sring, 0, (size_t)8 * RING * SLAB * 2, stream);
    hipMemsetAsync(flags, 0, (size_t)16 * FSTR * 4, stream);

    prep_xs <<<(T_STEPS * B_SZ * XK + 255) / 256, 256, 0, stream>>>(xs, xs_pad);
    pack_w0 <<<(N0PAD * K0 + 255) / 256, 256, 0, stream>>>(Wih0, Whh0, Wc0);
    pack_w1 <<<(N1PAD * K1 + 255) / 256, 256, 0, stream>>>(Wih1, Whh1, Wc1);
    pack_bias<<<(N0PAD + 255) / 256, 256, 0, stream>>>(bih0, bhh0, b0, N0PAD);
    pack_bias<<<(N1PAD + 255) / 256, 256, 0, stream>>>(bih1, bhh1, b1, N1PAD);

    // dynamic LDS: max(W0 slice 147456 B, W1 slice 129024 B)
    hipFuncSetAttribute((const void*)persist,
                        hipFuncAttributeMaxDynamicSharedMemorySize, 147456);
    void* args[] = { (void*)&xs_pad, (void*)&Wc0, (void*)&Wc1, (void*)&b0,
                     (void*)&b1, (void*)&Sring, (void*)&flags };
    hipLaunchCooperativeKernel((const void*)persist, dim3(NBLK), dim3(512),
                               args, 147456, stream);

    classifier<<<B_SZ / 4, 256, 0, stream>>>(Sring, Wout, bout, out);
}